// Round 3
// baseline (1831.528 us; speedup 1.0000x reference)
//
#include <hip/hip_runtime.h>
#include <hip/hip_bf16.h>
#include <math.h>

#define T_TOK 65536
#define C_DIM 1024
#define H_DIM 512
#define Q_DIM 256

typedef __attribute__((ext_vector_type(8))) _Float16 half8;
typedef __attribute__((ext_vector_type(4))) float f32x4;
typedef unsigned int u32;
typedef unsigned short u16;

#define MFMAF(a, b, c) __builtin_amdgcn_mfma_f32_16x16x32_f16((a), (b), (c), 0, 0, 0)

#define WS_B1H 0u
#define WS_B1L (WS_B1H + 1048576u)
#define WS_B2H (WS_B1L + 1048576u)
#define WS_B2L (WS_B2H + 524288u)
#define WS_B3H (WS_B2L + 524288u)
#define WS_B3L (WS_B3H + 262144u)
#define WS_BIAS2 (WS_B3L + 262144u)
#define WS_CNT  (WS_BIAS2 + 2048u)
#define WS_LIST (WS_CNT + 256u)
#define WS_W3   (WS_LIST + 32768u)
#define WS_NEED (WS_W3 + 1024u)

#define RC_CAP 8192
// fp16x3 split (weights x32, act-lo x2048, separate residual acc): z-error
// ~1e-6. eps=5e-5 PASSED on hardware in round 2 (same numerics) — keep it.
#define RC_EPS 5e-5f

__device__ __forceinline__ float gelu_exact(float x) {
    return 0.5f * x * (1.0f + erff(x * 0.70710678118654752440f));
}
// activation split: a = ah + al/2048 (lo stored x2048 so it stays normal-range)
__device__ __forceinline__ void split_a(float f, u16& hi, u16& lo) {
    _Float16 h = (_Float16)f;
    _Float16 l = (_Float16)((f - (float)h) * 2048.0f);
    hi = __builtin_bit_cast(u16, h);
    lo = __builtin_bit_cast(u16, l);
}
// weight split (input already x32 so lo plane is normal-range): w = wh + wl
__device__ __forceinline__ void split_w(float f, u16& hi, u16& lo) {
    _Float16 h = (_Float16)f;
    _Float16 l = (_Float16)(f - (float)h);
    hi = __builtin_bit_cast(u16, h);
    lo = __builtin_bit_cast(u16, l);
}
// combine: value = (acc_main + acc_res/2048) / 32
__device__ __forceinline__ float comb(float m, float r) {
    return fmaf(r, 4.8828125e-4f, m) * 0.03125f;
}

// pack weights (x32, fp16 hi/lo) into MFMA B-fragment layout; zero recheck counter
__global__ __launch_bounds__(256) void pack_kernel(const float* __restrict__ WL,
                                                   const float* __restrict__ Wl1,
                                                   const float* __restrict__ Wl2,
                                                   const float* __restrict__ w3,
                                                   unsigned char* __restrict__ ws) {
    u16* B1h = (u16*)(ws + WS_B1H); u16* B1l = (u16*)(ws + WS_B1L);
    u16* B2h = (u16*)(ws + WS_B2H); u16* B2l = (u16*)(ws + WS_B2L);
    u16* B3h = (u16*)(ws + WS_B3H); u16* B3l = (u16*)(ws + WS_B3L);
    int gid = blockIdx.x * 256 + threadIdx.x;
    if (gid == 0) *(int*)(ws + WS_CNT) = 0;
    if (gid < 256) ((float*)(ws + WS_W3))[gid] = w3[gid];
    int lane = gid & 63;
    int tg = gid >> 6;
    int kq = lane >> 4;
    int nn = lane & 15;
    if (tg < 1024) {
        int nt = tg >> 5, kt = tg & 31;
        int n = nt * 16 + nn;
        #pragma unroll
        for (int j = 0; j < 8; ++j) {
            int k = kt * 32 + kq * 8 + j;
            u16 h, l; split_w(WL[(size_t)k * 512 + n] * 32.0f, h, l);
            B1h[(size_t)tg * 512 + lane * 8 + j] = h;
            B1l[(size_t)tg * 512 + lane * 8 + j] = l;
        }
    } else if (tg < 1536) {
        int t2 = tg - 1024;
        int nt = t2 >> 4, kt = t2 & 15;
        int n = nt * 16 + nn;
        #pragma unroll
        for (int j = 0; j < 8; ++j) {
            int k = kt * 32 + kq * 8 + j;
            u16 h, l; split_w(Wl1[(size_t)k * 512 + n] * 32.0f, h, l);
            B2h[(size_t)t2 * 512 + lane * 8 + j] = h;
            B2l[(size_t)t2 * 512 + lane * 8 + j] = l;
        }
    } else if (tg < 1792) {
        int t3 = tg - 1536;
        int nt = t3 >> 4, kt = t3 & 15;
        int n = nt * 16 + nn;
        #pragma unroll
        for (int j = 0; j < 8; ++j) {
            int k = kt * 32 + kq * 8 + j;
            u16 h, l; split_w(Wl2[(size_t)k * 256 + n] * 32.0f, h, l);
            B3h[(size_t)t3 * 512 + lane * 8 + j] = h;
            B3l[(size_t)t3 * 512 + lane * 8 + j] = l;
        }
    }
}

__global__ void bias2_kernel(const float* __restrict__ nf,
                             const float* __restrict__ Wl1,
                             float* __restrict__ bias2) {
    int n = blockIdx.x * blockDim.x + threadIdx.x;
    if (n >= H_DIM) return;
    float s = 0.0f;
    #pragma unroll 8
    for (int j = 0; j < H_DIM; ++j)
        s = fmaf(nf[j], Wl1[(size_t)(H_DIM + j) * H_DIM + n], s);
    bias2[n] = s;
}

// MTOK=64, 1 block/CU (proven no-spill envelope, cap 256 regs via bounds(512,2)).
// GEMM1 staging is double-buffered: ONE barrier per chunk, next-chunk x-loads
// issued before the barrier so HBM latency hides under the MFMA phase.
#define MTOK 64
#define SA_STR 136
#define SH_STR 520
#define S3_STR 260

__device__ __forceinline__ void stage_proc(u16* __restrict__ dAh, u16* __restrict__ dAl,
                                           const float4* xv, int tid, int chunk,
                                           const float* __restrict__ sMu,
                                           const float* __restrict__ sRs,
                                           const float* __restrict__ gamma,
                                           const float* __restrict__ beta) {
    #pragma unroll
    for (int i = 0; i < 4; ++i) {
        int fq = tid + (i << 9);
        int row = fq >> 5, kq = fq & 31;
        float mu = sMu[row], rs = sRs[row];
        int gk = chunk * 128 + kq * 4;
        float4 v = xv[i];
        float a0 = fmaf((v.x - mu) * rs, gamma[gk],     beta[gk]);
        float a1 = fmaf((v.y - mu) * rs, gamma[gk + 1], beta[gk + 1]);
        float a2 = fmaf((v.z - mu) * rs, gamma[gk + 2], beta[gk + 2]);
        float a3 = fmaf((v.w - mu) * rs, gamma[gk + 3], beta[gk + 3]);
        u16 h0, l0, h1, l1, h2, l2, h3, l3;
        split_a(a0, h0, l0); split_a(a1, h1, l1);
        split_a(a2, h2, l2); split_a(a3, h3, l3);
        uint2 ph = make_uint2((u32)h0 | ((u32)h1 << 16), (u32)h2 | ((u32)h3 << 16));
        uint2 pl = make_uint2((u32)l0 | ((u32)l1 << 16), (u32)l2 | ((u32)l3 << 16));
        *(uint2*)&dAh[row * SA_STR + kq * 4] = ph;
        *(uint2*)&dAl[row * SA_STR + kq * 4] = pl;
    }
}

__global__ __launch_bounds__(512, 2)
void chanFSM_mfma_kernel(const float* __restrict__ x,
                         const float* __restrict__ prev_m,
                         const float* __restrict__ gamma,
                         const float* __restrict__ beta,
                         const unsigned char* __restrict__ ws,
                         float* __restrict__ out,
                         float* __restrict__ out_mask,
                         float* __restrict__ out_curr) {
    __shared__ __align__(16) unsigned char smem[133120];
    __shared__ float sMu[MTOK], sRs[MTOK], sFlag[MTOK];
    __shared__ float sBias[H_DIM];
    __shared__ float sw3[Q_DIM];

    // sA double buffer (4 x 64*136 u16 = 69.6KB) aliases the low part of smem;
    // sHh/sHl (133KB) reuse the whole region after GEMM1 completes.
    u16* sA[4];
    sA[0] = (u16*)smem;                    // Ah buf0
    sA[1] = sA[0] + MTOK * SA_STR;         // Al buf0
    sA[2] = sA[1] + MTOK * SA_STR;         // Ah buf1
    sA[3] = sA[2] + MTOK * SA_STR;         // Al buf1
    u16* sHh = (u16*)smem;
    u16* sHl = sHh + MTOK * SH_STR;
    float* sH3 = (float*)smem;

    const u16* B1h = (const u16*)(ws + WS_B1H); const u16* B1l = (const u16*)(ws + WS_B1L);
    const u16* B2h = (const u16*)(ws + WS_B2H); const u16* B2l = (const u16*)(ws + WS_B2L);
    const u16* B3h = (const u16*)(ws + WS_B3H); const u16* B3l = (const u16*)(ws + WS_B3L);
    int* rc_cnt  = (int*)(ws + WS_CNT);
    int* rc_list = (int*)(ws + WS_LIST);

    const int tid = threadIdx.x;
    const int t0  = blockIdx.x * MTOK;
    const int wid = tid >> 6;
    const int ln  = tid & 63;
    const int rg  = wid & 1;
    const int cg  = wid >> 1;
    const int lm  = ln & 15;
    const int lq  = ln >> 4;

    if (tid < H_DIM) sBias[tid] = ((const float*)(ws + WS_BIAS2))[tid];
    if (tid < Q_DIM) sw3[tid] = ((const float*)(ws + WS_W3))[tid];

    // Phase 1: LN stats (8 rows per wave)
    for (int m = wid * 8; m < wid * 8 + 8; ++m) {
        const float* row = x + (size_t)(t0 + m) * C_DIM;
        double ds = 0.0, dq = 0.0;
        #pragma unroll
        for (int j = 0; j < 16; ++j) {
            float v = row[ln + (j << 6)];
            ds += (double)v; dq += (double)v * (double)v;
        }
        #pragma unroll
        for (int off = 32; off > 0; off >>= 1) {
            ds += __shfl_down(ds, off);
            dq += __shfl_down(dq, off);
        }
        if (ln == 0) {
            double mu = ds * (1.0 / 1024.0);
            double var = dq * (1.0 / 1024.0) - mu * mu;
            sMu[m] = (float)mu;
            sRs[m] = 1.0f / sqrtf((float)var + 1e-5f);
        }
    }

    // Phase 2: GEMM1 (K=1024, 8 chunks of 128, double-buffered staging)
    f32x4 acc_m[2][8], acc_r[2][8];
    #pragma unroll
    for (int rt = 0; rt < 2; ++rt)
        #pragma unroll
        for (int c = 0; c < 8; ++c) {
            acc_m[rt][c] = (f32x4){0.f, 0.f, 0.f, 0.f};
            acc_r[rt][c] = (f32x4){0.f, 0.f, 0.f, 0.f};
        }

    float4 xv[4];
    // prologue: load chunk 0
    #pragma unroll
    for (int i = 0; i < 4; ++i) {
        int fq = tid + (i << 9);
        int row = fq >> 5, kq = fq & 31;
        xv[i] = *(const float4*)&x[(size_t)(t0 + row) * C_DIM + kq * 4];
    }
    __syncthreads();   // sMu/sRs ready
    stage_proc(sA[0], sA[1], xv, tid, 0, sMu, sRs, gamma, beta);

    for (int ch = 0; ch < 8; ++ch) {
        // issue next-chunk loads before the barrier: latency hides under MFMA
        if (ch < 7) {
            #pragma unroll
            for (int i = 0; i < 4; ++i) {
                int fq = tid + (i << 9);
                int row = fq >> 5, kq = fq & 31;
                xv[i] = *(const float4*)&x[(size_t)(t0 + row) * C_DIM + (ch + 1) * 128 + kq * 4];
            }
        }
        __syncthreads();   // sA[ch&1] writes visible to all waves
        const u16* pAh = sA[(ch & 1) * 2];
        const u16* pAl = sA[(ch & 1) * 2 + 1];

        #pragma unroll
        for (int kt = 0; kt < 4; ++kt) {
            half8 ah[2], al[2];
            #pragma unroll
            for (int rt = 0; rt < 2; ++rt) {
                int row = rg * 32 + rt * 16 + lm;
                ah[rt] = *(const half8*)&pAh[row * SA_STR + kt * 32 + lq * 8];
                al[rt] = *(const half8*)&pAl[row * SA_STR + kt * 32 + lq * 8];
            }
            int ktg = ch * 4 + kt;
            #pragma unroll
            for (int chf = 0; chf < 2; ++chf) {
                half8 bh[4], bl[4];
                #pragma unroll
                for (int c = 0; c < 4; ++c) {
                    int tile = (cg * 8 + chf * 4 + c) * 32 + ktg;
                    bh[c] = *(const half8*)&B1h[(size_t)tile * 512 + ln * 8];
                    bl[c] = *(const half8*)&B1l[(size_t)tile * 512 + ln * 8];
                }
                #pragma unroll
                for (int c = 0; c < 4; ++c)
                    #pragma unroll
                    for (int rt = 0; rt < 2; ++rt) {
                        int cc = chf * 4 + c;
                        acc_m[rt][cc] = MFMAF(ah[rt], bh[c], acc_m[rt][cc]);
                        acc_m[rt][cc] = MFMAF(ah[rt], bl[c], acc_m[rt][cc]);
                        acc_r[rt][cc] = MFMAF(al[rt], bh[c], acc_r[rt][cc]);
                    }
            }
        }
        if (ch < 7)
            stage_proc(sA[((ch + 1) & 1) * 2], sA[((ch + 1) & 1) * 2 + 1],
                       xv, tid, ch + 1, sMu, sRs, gamma, beta);
    }
    __syncthreads();
    #pragma unroll
    for (int rt = 0; rt < 2; ++rt)
        #pragma unroll
        for (int c = 0; c < 8; ++c) {
            int col = (cg * 8 + c) * 16 + lm;
            #pragma unroll
            for (int r = 0; r < 4; ++r) {
                int row = rg * 32 + rt * 16 + lq * 4 + r;
                u16 h, l; split_a(gelu_exact(comb(acc_m[rt][c][r], acc_r[rt][c][r])), h, l);
                sHh[row * SH_STR + col] = h;
                sHl[row * SH_STR + col] = l;
            }
        }
    __syncthreads();

    // Phase 3: GEMM2 (K=512) + bias2 (seeded in x32 domain)
    f32x4 acc2_m[2][8], acc2_r[2][8];
    #pragma unroll
    for (int rt = 0; rt < 2; ++rt)
        #pragma unroll
        for (int c = 0; c < 8; ++c) {
            float b = sBias[(cg * 8 + c) * 16 + lm] * 32.0f;
            acc2_m[rt][c] = (f32x4){b, b, b, b};
            acc2_r[rt][c] = (f32x4){0.f, 0.f, 0.f, 0.f};
        }
    #pragma unroll 2
    for (int kt = 0; kt < 16; ++kt) {
        half8 ah[2], al[2];
        #pragma unroll
        for (int rt = 0; rt < 2; ++rt) {
            int row = rg * 32 + rt * 16 + lm;
            ah[rt] = *(const half8*)&sHh[row * SH_STR + kt * 32 + lq * 8];
            al[rt] = *(const half8*)&sHl[row * SH_STR + kt * 32 + lq * 8];
        }
        #pragma unroll
        for (int chf = 0; chf < 2; ++chf) {
            half8 bh[4], bl[4];
            #pragma unroll
            for (int c = 0; c < 4; ++c) {
                int tile = (cg * 8 + chf * 4 + c) * 16 + kt;
                bh[c] = *(const half8*)&B2h[(size_t)tile * 512 + ln * 8];
                bl[c] = *(const half8*)&B2l[(size_t)tile * 512 + ln * 8];
            }
            #pragma unroll
            for (int c = 0; c < 4; ++c)
                #pragma unroll
                for (int rt = 0; rt < 2; ++rt) {
                    int cc = chf * 4 + c;
                    acc2_m[rt][cc] = MFMAF(ah[rt], bh[c], acc2_m[rt][cc]);
                    acc2_m[rt][cc] = MFMAF(ah[rt], bl[c], acc2_m[rt][cc]);
                    acc2_r[rt][cc] = MFMAF(al[rt], bh[c], acc2_r[rt][cc]);
                }
        }
    }
    __syncthreads();
    #pragma unroll
    for (int rt = 0; rt < 2; ++rt)
        #pragma unroll
        for (int c = 0; c < 8; ++c) {
            int col = (cg * 8 + c) * 16 + lm;
            #pragma unroll
            for (int r = 0; r < 4; ++r) {
                int row = rg * 32 + rt * 16 + lq * 4 + r;
                u16 h, l; split_a(gelu_exact(comb(acc2_m[rt][c][r], acc2_r[rt][c][r])), h, l);
                sHh[row * SH_STR + col] = h;
                sHl[row * SH_STR + col] = l;
            }
        }
    __syncthreads();

    // Phase 4: GEMM3 (K=512, N=256)
    f32x4 acc3_m[2][4], acc3_r[2][4];
    #pragma unroll
    for (int rt = 0; rt < 2; ++rt)
        #pragma unroll
        for (int c = 0; c < 4; ++c) {
            acc3_m[rt][c] = (f32x4){0.f, 0.f, 0.f, 0.f};
            acc3_r[rt][c] = (f32x4){0.f, 0.f, 0.f, 0.f};
        }
    #pragma unroll 2
    for (int kt = 0; kt < 16; ++kt) {
        half8 ah[2], al[2];
        #pragma unroll
        for (int rt = 0; rt < 2; ++rt) {
            int row = rg * 32 + rt * 16 + lm;
            ah[rt] = *(const half8*)&sHh[row * SH_STR + kt * 32 + lq * 8];
            al[rt] = *(const half8*)&sHl[row * SH_STR + kt * 32 + lq * 8];
        }
        half8 bh[4], bl[4];
        #pragma unroll
        for (int c = 0; c < 4; ++c) {
            int tile = (cg * 4 + c) * 16 + kt;
            bh[c] = *(const half8*)&B3h[(size_t)tile * 512 + ln * 8];
            bl[c] = *(const half8*)&B3l[(size_t)tile * 512 + ln * 8];
        }
        #pragma unroll
        for (int c = 0; c < 4; ++c)
            #pragma unroll
            for (int rt = 0; rt < 2; ++rt) {
                acc3_m[rt][c] = MFMAF(ah[rt], bh[c], acc3_m[rt][c]);
                acc3_m[rt][c] = MFMAF(ah[rt], bl[c], acc3_m[rt][c]);
                acc3_r[rt][c] = MFMAF(al[rt], bh[c], acc3_r[rt][c]);
            }
    }
    __syncthreads();
    #pragma unroll
    for (int rt = 0; rt < 2; ++rt)
        #pragma unroll
        for (int c = 0; c < 4; ++c) {
            int col = (cg * 4 + c) * 16 + lm;
            #pragma unroll
            for (int r = 0; r < 4; ++r) {
                int row = rg * 32 + rt * 16 + lq * 4 + r;
                sH3[row * S3_STR + col] = gelu_exact(comb(acc3_m[rt][c][r], acc3_r[rt][c][r]));
            }
        }
    __syncthreads();

    // Phase 5: GEMM4 + sigmoid + STE + recheck flag
    for (int m = wid * 8; m < wid * 8 + 8; ++m) {
        float z = 0.0f;
        #pragma unroll
        for (int j = 0; j < 4; ++j) {
            int k = ln + (j << 6);
            z = fmaf(sH3[m * S3_STR + k], sw3[k], z);
        }
        #pragma unroll
        for (int off = 32; off > 0; off >>= 1) z += __shfl_down(z, off);
        if (ln == 0) {
            float prob = 1.0f / (1.0f + expf(-z));
            float t = prob * prev_m[t0 + m];
            float c = (t > 0.5f) ? 1.0f : 0.0f;
            sFlag[m] = c;
            out_mask[t0 + m] = c;
            out_curr[t0 + m] = (c > 0.0f) ? 1.0f : 1e-10f;
            if (fabsf(t - 0.5f) < RC_EPS) {
                int i = atomicAdd(rc_cnt, 1);
                if (i < RC_CAP) rc_list[i] = t0 + m;
            }
        }
    }
    __syncthreads();

    // Phase 6: out = x * curr_m
    const float4* x4 = (const float4*)(x   + (size_t)t0 * C_DIM);
    float4*       o4 = (float4*)      (out + (size_t)t0 * C_DIM);
    #pragma unroll 4
    for (int i = 0; i < 32; ++i) {
        int idx = tid + (i << 9);
        int m = idx >> 8;
        float c = sFlag[m];
        float4 v = x4[idx];
        v.x *= c; v.y *= c; v.z *= c; v.w *= c;
        o4[idx] = v;
    }
}

// fp32 exact recheck — 16 tokens/block, 512 threads. Per-OUTPUT fp arithmetic
// is BIT-IDENTICAL to the passing version: per-column k-mod-4 4-acc split,
// (s0+s1)+(s2+s3) combine, fp64 LN stats with the same 256-thread/4-wave
// shuffle shape (replicated per 256-thread group), GEMM4 wave tree +
// left-assoc double combine. Only thread/block assignment changed.
__global__ __launch_bounds__(512)
void recheck_kernel(const float* __restrict__ x, const float* __restrict__ prev_m,
                    const float* __restrict__ gamma, const float* __restrict__ beta,
                    const float* __restrict__ WL, const float* __restrict__ Wl1,
                    const float* __restrict__ Wl2, const float* __restrict__ w3,
                    const unsigned char* __restrict__ ws,
                    float* __restrict__ out, float* __restrict__ out_mask,
                    float* __restrict__ out_curr) {
    __shared__ __align__(16) float sx[16 * 1024];
    __shared__ __align__(16) float sh1[16 * 512];
    __shared__ __align__(16) float sh2[16 * 512];
    __shared__ __align__(16) float sh3[16 * 256];
    __shared__ double srA[16][4], srB[16][4];
    __shared__ float sMu[16], sRs[16], sFlag[16];
    __shared__ int sTok[16];

    const float* bias2 = (const float*)(ws + WS_BIAS2);
    const int* cnt = (const int*)(ws + WS_CNT);
    const int* list = (const int*)(ws + WS_LIST);
    int n = *cnt; if (n > RC_CAP) n = RC_CAP;
    if (blockIdx.x * 16 >= n) return;

    const int tid = threadIdx.x;
    const int grp = tid >> 8;        // 0/1: token half
    const int t8  = tid & 255;       // index within 256-thread group
    const int wid8 = t8 >> 6;        // wave-in-group 0..3
    const int ln  = tid & 63;

    if (tid < 16) {
        int it = blockIdx.x * 16 + tid;
        sTok[tid] = (it < n) ? list[it] : -1;
    }
    __syncthreads();

    // stage 16 token rows
    #pragma unroll
    for (int g = 0; g < 16; ++g) {
        int tk = sTok[g];
        if (tk >= 0) {
            const float* row = x + (size_t)tk * C_DIM;
            sx[g * 1024 + tid]       = row[tid];
            sx[g * 1024 + tid + 512] = row[tid + 512];
        } else {
            sx[g * 1024 + tid] = 0.f;
            sx[g * 1024 + tid + 512] = 0.f;
        }
    }
    __syncthreads();

    // LN stats — each 256-thread group replicates the original scheme on its 8 tokens
    #pragma unroll
    for (int gg = 0; gg < 8; ++gg) {
        int g = grp * 8 + gg;
        double ds = 0.0, dq = 0.0;
        #pragma unroll
        for (int j = 0; j < 4; ++j) {
            float v = sx[g * 1024 + t8 + (j << 8)];
            ds += (double)v; dq += (double)v * (double)v;
        }
        #pragma unroll
        for (int off = 32; off > 0; off >>= 1) {
            ds += __shfl_down(ds, off); dq += __shfl_down(dq, off);
        }
        if (ln == 0) { srA[g][wid8] = ds; srB[g][wid8] = dq; }
    }
    __syncthreads();
    if (tid < 16) {
        double tds = srA[tid][0] + srA[tid][1] + srA[tid][2] + srA[tid][3];
        double tdq = srB[tid][0] + srB[tid][1] + srB[tid][2] + srB[tid][3];
        double mud = tds * (1.0 / 1024.0);
        sMu[tid] = (float)mud;
        sRs[tid] = 1.0f / sqrtf((float)(tdq * (1.0 / 1024.0) - mud * mud) + 1e-5f);
    }
    __syncthreads();
    #pragma unroll
    for (int g = 0; g < 16; ++g) {
        float mu = sMu[g], rs = sRs[g];
        int k0 = tid, k1 = tid + 512;
        sx[g * 1024 + k0] = fmaf((sx[g * 1024 + k0] - mu) * rs, gamma[k0], beta[k0]);
        sx[g * 1024 + k1] = fmaf((sx[g * 1024 + k1] - mu) * rs, gamma[k1], beta[k1]);
    }
    __syncthreads();

    // GEMM1: [16 tok] x (1024 -> 512); thread owns col tid
    {
        float acc[16][4];
        #pragma unroll
        for (int g = 0; g < 16; ++g)
            #pragma unroll
            for (int i = 0; i < 4; ++i) acc[g][i] = 0.f;
        const float* Wp = WL + tid;
        #pragma unroll 4
        for (int k = 0; k < 1024; k += 4) {
            float w0 = Wp[(size_t)(k + 0) * 512];
            float w1 = Wp[(size_t)(k + 1) * 512];
            float w2 = Wp[(size_t)(k + 2) * 512];
            float w3v = Wp[(size_t)(k + 3) * 512];
            #pragma unroll
            for (int g = 0; g < 16; ++g) {
                float4 a = *(const float4*)&sx[g * 1024 + k];
                acc[g][0] = fmaf(a.x, w0, acc[g][0]);
                acc[g][1] = fmaf(a.y, w1, acc[g][1]);
                acc[g][2] = fmaf(a.z, w2, acc[g][2]);
                acc[g][3] = fmaf(a.w, w3v, acc[g][3]);
            }
        }
        #pragma unroll
        for (int g = 0; g < 16; ++g)
            sh1[g * 512 + tid] = gelu_exact((acc[g][0] + acc[g][1]) + (acc[g][2] + acc[g][3]));
    }
    __syncthreads();

    // GEMM2: [16 tok] x (512 -> 512) + bias2 (bias seeds the k%4==0 chain)
    {
        float acc[16][4];
        float b2 = bias2[tid];
        #pragma unroll
        for (int g = 0; g < 16; ++g) {
            acc[g][0] = b2;
            acc[g][1] = 0.f; acc[g][2] = 0.f; acc[g][3] = 0.f;
        }
        const float* Wp = Wl1 + tid;
        #pragma unroll 4
        for (int k = 0; k < 512; k += 4) {
            float w0 = Wp[(size_t)(k + 0) * 512];
            float w1 = Wp[(size_t)(k + 1) * 512];
            float w2 = Wp[(size_t)(k + 2) * 512];
            float w3v = Wp[(size_t)(k + 3) * 512];
            #pragma unroll
            for (int g = 0; g < 16; ++g) {
                float4 a = *(const float4*)&sh1[g * 512 + k];
                acc[g][0] = fmaf(a.x, w0, acc[g][0]);
                acc[g][1] = fmaf(a.y, w1, acc[g][1]);
                acc[g][2] = fmaf(a.z, w2, acc[g][2]);
                acc[g][3] = fmaf(a.w, w3v, acc[g][3]);
            }
        }
        #pragma unroll
        for (int g = 0; g < 16; ++g)
            sh2[g * 512 + tid] = gelu_exact((acc[g][0] + acc[g][1]) + (acc[g][2] + acc[g][3]));
    }
    __syncthreads();

    // GEMM3: [16 tok] x (512 -> 256); group g handles its 8 tokens, thread owns col t8
    {
        float acc[8][4];
        #pragma unroll
        for (int gg = 0; gg < 8; ++gg)
            #pragma unroll
            for (int i = 0; i < 4; ++i) acc[gg][i] = 0.f;
        const float* Wp = Wl2 + t8;
        #pragma unroll 4
        for (int k = 0; k < 512; k += 4) {
            float w0 = Wp[(size_t)(k + 0) * 256];
            float w1 = Wp[(size_t)(k + 1) * 256];
            float w2 = Wp[(size_t)(k + 2) * 256];
            float w3v = Wp[(size_t)(k + 3) * 256];
            #pragma unroll
            for (int gg = 0; gg < 8; ++gg) {
                float4 a = *(const float4*)&sh2[(grp * 8 + gg) * 512 + k];
                acc[gg][0] = fmaf(a.x, w0, acc[gg][0]);
                acc[gg][1] = fmaf(a.y, w1, acc[gg][1]);
                acc[gg][2] = fmaf(a.z, w2, acc[gg][2]);
                acc[gg][3] = fmaf(a.w, w3v, acc[gg][3]);
            }
        }
        #pragma unroll
        for (int gg = 0; gg < 8; ++gg)
            sh3[(grp * 8 + gg) * 256 + t8] =
                gelu_exact((acc[gg][0] + acc[gg][1]) + (acc[gg][2] + acc[gg][3]));
    }
    __syncthreads();

    // GEMM4: per-token wave tree (same shape as original)
    {
        float zz[8];
        float wv = w3[t8];
        #pragma unroll
        for (int gg = 0; gg < 8; ++gg) zz[gg] = sh3[(grp * 8 + gg) * 256 + t8] * wv;
        #pragma unroll
        for (int off = 32; off > 0; off >>= 1) {
            #pragma unroll
            for (int gg = 0; gg < 8; ++gg) zz[gg] += __shfl_down(zz[gg], off);
        }
        if (ln == 0) {
            #pragma unroll
            for (int gg = 0; gg < 8; ++gg) srA[grp * 8 + gg][wid8] = (double)zz[gg];
        }
    }
    __syncthreads();
    if (tid < 16) {
        int tk = sTok[tid];
        if (tk >= 0) {
            float z = (float)(srA[tid][0] + srA[tid][1] + srA[tid][2] + srA[tid][3]);
            float prob = 1.0f / (1.0f + expf(-z));
            float t = prob * prev_m[tk];
            float c = (t > 0.5f) ? 1.0f : 0.0f;
            out_mask[tk] = c;
            out_curr[tk] = (c > 0.0f) ? 1.0f : 1e-10f;
            sFlag[tid] = c;
        }
    }
    __syncthreads();
    #pragma unroll
    for (int gg = 0; gg < 8; ++gg) {
        int g = grp * 8 + gg;
        int tk = sTok[g];
        if (tk < 0) continue;
        float c = sFlag[g];
        float4 v = ((const float4*)(x + (size_t)tk * C_DIM))[t8];
        v.x *= c; v.y *= c; v.z *= c; v.w *= c;
        ((float4*)(out + (size_t)tk * C_DIM))[t8] = v;
    }
}

extern "C" void kernel_launch(void* const* d_in, const int* in_sizes, int n_in,
                              void* d_out, int out_size, void* d_ws, size_t ws_size,
                              hipStream_t stream) {
    const float* x      = (const float*)d_in[0];
    const float* nf     = (const float*)d_in[1];
    const float* prev_m = (const float*)d_in[2];
    const float* gamma  = (const float*)d_in[3];
    const float* beta   = (const float*)d_in[4];
    const float* WL     = (const float*)d_in[5];
    const float* Wl1    = (const float*)d_in[6];
    const float* Wl2    = (const float*)d_in[7];
    const float* w3     = (const float*)d_in[8];

    float* out      = (float*)d_out;
    float* out_mask = out + (size_t)T_TOK * C_DIM;
    float* out_curr = out_mask + T_TOK;

    unsigned char* ws = (unsigned char*)d_ws;

    pack_kernel<<<448, 256, 0, stream>>>(WL, Wl1, Wl2, w3, ws);
    bias2_kernel<<<1, 512, 0, stream>>>(nf, Wl1, (float*)(ws + WS_BIAS2));

    chanFSM_mfma_kernel<<<T_TOK / MTOK, 512, 0, stream>>>(
        x, prev_m, gamma, beta, ws, out, out_mask, out_curr);

    recheck_kernel<<<RC_CAP / 16, 512, 0, stream>>>(
        x, prev_m, gamma, beta, WL, Wl1, Wl2, w3, ws, out, out_mask, out_curr);
}